// Round 5
// baseline (2797.928 us; speedup 1.0000x reference)
//
#include <hip/hip_runtime.h>
#include <hip/hip_bf16.h>

// LayerRouter: relu(x@w1+b1)@w2 -> softmax -> top2 -> soft mask [M,8] + aux.
// M=16384, K(H)=4096, N(MID)=2048, E=8, fp32 in/out.
//
// Round 8: LDS-FREE direct-fragment GEMM. Rounds 5-7 proved the wall is
// barrier lockstep (every schedule variant: MfmaUtil 22-31%, both pipes idle
// >50%). The MFMA fragment pattern (16 rows x 64B) is exactly 1 cache line
// per row -> load fragments straight from global (L2/L3-resident) into
// registers, double-buffered (fa/fb, static names). No LDS, no barriers,
// no inline asm: loads for step k+1 issue before step k's 48 MFMAs, the
// compiler inserts counted vmcnt, waves never collectively stall.

#define NE 8
#define BM 128
#define BN 128
#define BK 32

typedef __attribute__((ext_vector_type(8))) short bf16x8;
typedef __attribute__((ext_vector_type(4))) float f32x4;

__device__ inline ushort f2bf_rne(float v) {
    unsigned x = __float_as_uint(v);
    unsigned r = (x + 0x7fffu + ((x >> 16) & 1u)) >> 16;
    return (ushort)r;
}
__device__ inline float bf2f(ushort u) {
    return __uint_as_float(((unsigned)u) << 16);
}

#define GLL16(gp, lp) __builtin_amdgcn_global_load_lds( \
    (const __attribute__((address_space(1))) unsigned*)(gp), \
    (__attribute__((address_space(3))) unsigned*)(lp), 16, 0, 0)

#define MFMA16(a, b, c) __builtin_amdgcn_mfma_f32_16x16x32_bf16((a), (b), (c), 0, 0, 0)

// ---------------- w1 [K][N] fp32 -> w1t_hi/lo [N][K] bf16 ----------------
__global__ __launch_bounds__(256) void decomp_w1(
    const float* __restrict__ w1, ushort* __restrict__ w1t_hi,
    ushort* __restrict__ w1t_lo, int K, int N)
{
    __shared__ float tile[32][33];
    const int k0 = blockIdx.y * 32, n0 = blockIdx.x * 32;
    const int t = threadIdx.x;
    {
        int k = t >> 3, n4 = (t & 7) * 4;
        float4 v = *(const float4*)&w1[(size_t)(k0 + k) * N + n0 + n4];
        tile[k][n4 + 0] = v.x; tile[k][n4 + 1] = v.y;
        tile[k][n4 + 2] = v.z; tile[k][n4 + 3] = v.w;
    }
    __syncthreads();
    {
        int n = t >> 3, k4 = (t & 7) * 4;
        ushort4 h, l;
        float v;
        v = tile[k4 + 0][n]; h.x = f2bf_rne(v); l.x = f2bf_rne(v - bf2f(h.x));
        v = tile[k4 + 1][n]; h.y = f2bf_rne(v); l.y = f2bf_rne(v - bf2f(h.y));
        v = tile[k4 + 2][n]; h.z = f2bf_rne(v); l.z = f2bf_rne(v - bf2f(h.z));
        v = tile[k4 + 3][n]; h.w = f2bf_rne(v); l.w = f2bf_rne(v - bf2f(h.w));
        *(ushort4*)&w1t_hi[(size_t)(n0 + n) * K + k0 + k4] = h;
        *(ushort4*)&w1t_lo[(size_t)(n0 + n) * K + k0 + k4] = l;
    }
}

// ---------------- x [M][K] fp32 -> xh/xl [M][K] bf16 (same layout) --------
__global__ __launch_bounds__(256) void decomp_x(
    const float* __restrict__ x, ushort* __restrict__ xh,
    ushort* __restrict__ xl, size_t total4)
{
    size_t i = (size_t)blockIdx.x * blockDim.x + threadIdx.x;
    const size_t stride = (size_t)gridDim.x * blockDim.x;
    for (; i < total4; i += stride) {
        float4 v = ((const float4*)x)[i];
        ushort4 h, l;
        h.x = f2bf_rne(v.x); l.x = f2bf_rne(v.x - bf2f(h.x));
        h.y = f2bf_rne(v.y); l.y = f2bf_rne(v.y - bf2f(h.y));
        h.z = f2bf_rne(v.z); l.z = f2bf_rne(v.z - bf2f(h.z));
        h.w = f2bf_rne(v.w); l.w = f2bf_rne(v.w - bf2f(h.w));
        ((ushort4*)xh)[i] = h;
        ((ushort4*)xl)[i] = l;
    }
}

struct Frags {
    bf16x8 ah[4], al[4], bh[4], bl[4];   // 64 VGPRs
};

// ---- bf16x3 MFMA GEMM, no LDS, direct global fragments, reg dbuf --------
__global__ __launch_bounds__(256, 2) void gemm_pre(
    const ushort* __restrict__ xh,      // [M][K] bf16 hi
    const ushort* __restrict__ xl,      // [M][K] bf16 lo
    const ushort* __restrict__ w1t_hi,  // [N][K]
    const ushort* __restrict__ w1t_lo,  // [N][K]
    const float* __restrict__ b1,       // [N]
    const float* __restrict__ w2,       // [N][NE]
    float* __restrict__ logits,         // [M][NE] atomic accumulate
    int M, int K, int N)
{
    const int t    = threadIdx.x;
    const int lane = t & 63, wave = t >> 6;
    const int wm   = wave >> 1, wn = wave & 1;
    const int quad = lane >> 4, l15 = lane & 15;

    // bijective XCD swizzle (nwg % 8 == 0): blocks on one XCD cover
    // contiguous logical tiles, n-fastest -> A-strip L2 locality.
    int nbx = gridDim.x, nwg = gridDim.x * gridDim.y;
    int bid = blockIdx.y * nbx + blockIdx.x;
    int swz = bid;
    if ((nwg & 7) == 0) swz = (bid & 7) * (nwg >> 3) + (bid >> 3);
    const int n0 = (swz % nbx) * BN;
    const int m0 = (swz / nbx) * BM;

    // Per-lane element offsets for the 8 fragment streams (shared by hi/lo).
    // Each frag load: 16 rows x 64B = one cache line per row, fully used.
    int aoff[4], boff[4];
    #pragma unroll
    for (int i = 0; i < 4; ++i)
        aoff[i] = (m0 + wm * 64 + i * 16 + l15) * K + quad * 8;
    #pragma unroll
    for (int j = 0; j < 4; ++j)
        boff[j] = (n0 + wn * 64 + j * 16 + l15) * K + quad * 8;

    f32x4 acc[4][4] = {};

    auto LOADF = [&](int k, Frags& f) {
        #pragma unroll
        for (int i = 0; i < 4; ++i) {
            f.ah[i] = *(const bf16x8*)(xh + aoff[i] + k);
            f.al[i] = *(const bf16x8*)(xl + aoff[i] + k);
        }
        #pragma unroll
        for (int j = 0; j < 4; ++j) {
            f.bh[j] = *(const bf16x8*)(w1t_hi + boff[j] + k);
            f.bl[j] = *(const bf16x8*)(w1t_lo + boff[j] + k);
        }
    };
    auto STEP = [&](const Frags& f) {
        #pragma unroll
        for (int i = 0; i < 4; ++i)
            #pragma unroll
            for (int j = 0; j < 4; ++j) {
                acc[i][j] = MFMA16(f.ah[i], f.bh[j], acc[i][j]);
                acc[i][j] = MFMA16(f.ah[i], f.bl[j], acc[i][j]);
                acc[i][j] = MFMA16(f.al[i], f.bh[j], acc[i][j]);
            }
    };

    Frags fa, fb;
    LOADF(0, fa);
    for (int k0 = 0; k0 < K; k0 += 2 * BK) {
        LOADF(k0 + BK, fb);              // issue next-step loads...
        STEP(fa);                        // ...then 48 MFMA hide their latency
        if (k0 + 2 * BK < K) LOADF(k0 + 2 * BK, fa);
        STEP(fb);
    }

    // ---- epilogue: h = relu(acc + b1); logits += h @ w2 ----
    // acc[i][j][r]: row = m0+wm*64+i*16+quad*4+r, col = n0+wn*64+j*16+l15
    float w2row[4][NE], b1v[4];
    #pragma unroll
    for (int j = 0; j < 4; ++j) {
        int n = n0 + wn * 64 + j * 16 + l15;
        b1v[j] = b1[n];
        float4 lo4 = *(const float4*)&w2[(size_t)n * NE + 0];
        float4 hi4 = *(const float4*)&w2[(size_t)n * NE + 4];
        w2row[j][0] = lo4.x; w2row[j][1] = lo4.y; w2row[j][2] = lo4.z; w2row[j][3] = lo4.w;
        w2row[j][4] = hi4.x; w2row[j][5] = hi4.y; w2row[j][6] = hi4.z; w2row[j][7] = hi4.w;
    }
    #pragma unroll
    for (int i = 0; i < 4; ++i) {
        #pragma unroll
        for (int r = 0; r < 4; ++r) {
            float s[NE];
            #pragma unroll
            for (int e = 0; e < NE; ++e) s[e] = 0.f;
            #pragma unroll
            for (int j = 0; j < 4; ++j) {
                float h = acc[i][j][r] + b1v[j];
                h = h > 0.f ? h : 0.f;
                #pragma unroll
                for (int e = 0; e < NE; ++e) s[e] = fmaf(h, w2row[j][e], s[e]);
            }
            #pragma unroll
            for (int e = 0; e < NE; ++e) {
                #pragma unroll
                for (int off = 8; off > 0; off >>= 1)
                    s[e] += __shfl_down(s[e], off, 16);
            }
            if (l15 == 0) {
                int m = m0 + wm * 64 + i * 16 + quad * 4 + r;
                #pragma unroll
                for (int e = 0; e < NE; ++e)
                    atomicAdd(&logits[(size_t)m * NE + e], s[e]);
            }
        }
    }
}

// ---- round-3 path: in-loop A conversion (fallback if ws can't hold xh/xl) --
__global__ __launch_bounds__(256) void gemm_bf16x3(
    const float* __restrict__ x,        // [M][K]
    const ushort* __restrict__ w1t_hi,  // [N][K]
    const ushort* __restrict__ w1t_lo,  // [N][K]
    const float* __restrict__ b1,       // [N]
    const float* __restrict__ w2,       // [N][NE]
    float* __restrict__ logits,         // [M][NE] atomic accumulate
    int M, int K, int N)
{
    __shared__ ushort Ah[BM][BK], Al[BM][BK];
    __shared__ ushort Bh[BN][BK], Bl[BN][BK];

    const int t    = threadIdx.x;
    const int lane = t & 63, wave = t >> 6;
    const int wm   = wave >> 1, wn = wave & 1;
    const int quad = lane >> 4, l15 = lane & 15;
    const int n0   = blockIdx.x * BN;
    const int m0   = blockIdx.y * BM;

    const int am = t >> 3, ak = (t & 7) * 4;
    const float* xg = &x[(size_t)(m0 + am) * K + ak];

    const int c0 = wave * 64 + lane;
    const int c1 = c0 + 256;
    const size_t bg0 = (size_t)(n0 + (c0 >> 2)) * K + (size_t)(c0 & 3) * 8;
    const size_t bg1 = (size_t)(n0 + (c1 >> 2)) * K + (size_t)(c1 & 3) * 8;
    ushort* const bh_base  = &Bh[0][0] + (size_t)(wave * 64) * 8;
    ushort* const bh_base1 = &Bh[0][0] + (size_t)(wave * 64 + 256) * 8;
    ushort* const bl_base  = &Bl[0][0] + (size_t)(wave * 64) * 8;
    ushort* const bl_base1 = &Bl[0][0] + (size_t)(wave * 64 + 256) * 8;

    f32x4 acc[4][4] = {};

    for (int k0 = 0; k0 < K; k0 += BK) {
        __syncthreads();
        GLL16(w1t_hi + bg0 + k0, bh_base);
        GLL16(w1t_hi + bg1 + k0, bh_base1);
        GLL16(w1t_lo + bg0 + k0, bl_base);
        GLL16(w1t_lo + bg1 + k0, bl_base1);
        #pragma unroll
        for (int p = 0; p < 4; ++p) {
            float4 v = *(const float4*)(xg + (size_t)p * 32 * K + k0);
            ushort4 h, l;
            h.x = f2bf_rne(v.x); l.x = f2bf_rne(v.x - bf2f(h.x));
            h.y = f2bf_rne(v.y); l.y = f2bf_rne(v.y - bf2f(h.y));
            h.z = f2bf_rne(v.z); l.z = f2bf_rne(v.z - bf2f(h.z));
            h.w = f2bf_rne(v.w); l.w = f2bf_rne(v.w - bf2f(h.w));
            *(ushort4*)&Ah[am + 32 * p][ak] = h;
            *(ushort4*)&Al[am + 32 * p][ak] = l;
        }
        __syncthreads();

        bf16x8 afh[4], afl[4], bfh[4], bfl[4];
        #pragma unroll
        for (int i = 0; i < 4; ++i) {
            afh[i] = *(const bf16x8*)&Ah[wm * 64 + i * 16 + l15][quad * 8];
            afl[i] = *(const bf16x8*)&Al[wm * 64 + i * 16 + l15][quad * 8];
        }
        #pragma unroll
        for (int j = 0; j < 4; ++j) {
            bfh[j] = *(const bf16x8*)&Bh[wn * 64 + j * 16 + l15][quad * 8];
            bfl[j] = *(const bf16x8*)&Bl[wn * 64 + j * 16 + l15][quad * 8];
        }
        #pragma unroll
        for (int i = 0; i < 4; ++i)
            #pragma unroll
            for (int j = 0; j < 4; ++j) {
                acc[i][j] = MFMA16(afh[i], bfh[j], acc[i][j]);
                acc[i][j] = MFMA16(afh[i], bfl[j], acc[i][j]);
                acc[i][j] = MFMA16(afl[i], bfh[j], acc[i][j]);
            }
    }

    float w2row[4][NE], b1v[4];
    #pragma unroll
    for (int j = 0; j < 4; ++j) {
        int n = n0 + wn * 64 + j * 16 + l15;
        b1v[j] = b1[n];
        float4 lo4 = *(const float4*)&w2[(size_t)n * NE + 0];
        float4 hi4 = *(const float4*)&w2[(size_t)n * NE + 4];
        w2row[j][0] = lo4.x; w2row[j][1] = lo4.y; w2row[j][2] = lo4.z; w2row[j][3] = lo4.w;
        w2row[j][4] = hi4.x; w2row[j][5] = hi4.y; w2row[j][6] = hi4.z; w2row[j][7] = hi4.w;
    }
    #pragma unroll
    for (int i = 0; i < 4; ++i) {
        #pragma unroll
        for (int r = 0; r < 4; ++r) {
            float s[NE];
            #pragma unroll
            for (int e = 0; e < NE; ++e) s[e] = 0.f;
            #pragma unroll
            for (int j = 0; j < 4; ++j) {
                float h = acc[i][j][r] + b1v[j];
                h = h > 0.f ? h : 0.f;
                #pragma unroll
                for (int e = 0; e < NE; ++e) s[e] = fmaf(h, w2row[j][e], s[e]);
            }
            #pragma unroll
            for (int e = 0; e < NE; ++e) {
                #pragma unroll
                for (int off = 8; off > 0; off >>= 1)
                    s[e] += __shfl_down(s[e], off, 16);
            }
            if (l15 == 0) {
                int m = m0 + wm * 64 + i * 16 + quad * 4 + r;
                #pragma unroll
                for (int e = 0; e < NE; ++e)
                    atomicAdd(&logits[(size_t)m * NE + e], s[e]);
            }
        }
    }
}

// ---------------- fp32 fallback GEMM (ws-size guard) ----------------
#define TM 64
#define TN 64
#define FBK 16

__global__ __launch_bounds__(256) void gemm1_fused(
    const float* __restrict__ x, const float* __restrict__ w1,
    const float* __restrict__ b1, const float* __restrict__ w2,
    float* __restrict__ logits, int M, int K, int N)
{
    __shared__ float As[FBK][TM + 4];
    __shared__ float Bs[FBK][TN];
    const int tid = threadIdx.x;
    const int tx = tid & 15, ty = tid >> 4;
    const int n0 = blockIdx.x * TN, m0 = blockIdx.y * TM;
    const int a_k = tid & 15, a_r = tid >> 4;
    const int b_n = tid & 63, b_k = tid >> 6;
    float acc[4][4] = {};
    for (int k0 = 0; k0 < K; k0 += FBK) {
        #pragma unroll
        for (int p = 0; p < 4; ++p) {
            int r = a_r + 16 * p;
            As[a_k][r] = x[(size_t)(m0 + r) * K + (k0 + a_k)];
        }
        #pragma unroll
        for (int p = 0; p < 4; ++p) {
            int k = b_k + 4 * p;
            Bs[k][b_n] = w1[(size_t)(k0 + k) * N + (n0 + b_n)];
        }
        __syncthreads();
        #pragma unroll
        for (int k = 0; k < FBK; ++k) {
            float a[4], b[4];
            #pragma unroll
            for (int i = 0; i < 4; ++i) a[i] = As[k][ty * 4 + i];
            #pragma unroll
            for (int j = 0; j < 4; ++j) b[j] = Bs[k][tx * 4 + j];
            #pragma unroll
            for (int i = 0; i < 4; ++i)
                #pragma unroll
                for (int j = 0; j < 4; ++j)
                    acc[i][j] = fmaf(a[i], b[j], acc[i][j]);
        }
        __syncthreads();
    }
    float part[4][NE];
    #pragma unroll
    for (int i = 0; i < 4; ++i)
        #pragma unroll
        for (int e = 0; e < NE; ++e) part[i][e] = 0.f;
    #pragma unroll
    for (int j = 0; j < 4; ++j) {
        int n = n0 + tx * 4 + j;
        float bias = b1[n];
        float4 wlo = *(const float4*)&w2[(size_t)n * NE + 0];
        float4 whi = *(const float4*)&w2[(size_t)n * NE + 4];
        #pragma unroll
        for (int i = 0; i < 4; ++i) {
            float h = acc[i][j] + bias;
            h = h > 0.f ? h : 0.f;
            part[i][0] = fmaf(h, wlo.x, part[i][0]);
            part[i][1] = fmaf(h, wlo.y, part[i][1]);
            part[i][2] = fmaf(h, wlo.z, part[i][2]);
            part[i][3] = fmaf(h, wlo.w, part[i][3]);
            part[i][4] = fmaf(h, whi.x, part[i][4]);
            part[i][5] = fmaf(h, whi.y, part[i][5]);
            part[i][6] = fmaf(h, whi.z, part[i][6]);
            part[i][7] = fmaf(h, whi.w, part[i][7]);
        }
    }
    #pragma unroll
    for (int i = 0; i < 4; ++i)
        #pragma unroll
        for (int e = 0; e < NE; ++e) {
            float v = part[i][e];
            #pragma unroll
            for (int off = 8; off > 0; off >>= 1) v += __shfl_down(v, off, 16);
            part[i][e] = v;
        }
    if (tx == 0)
        #pragma unroll
        for (int i = 0; i < 4; ++i) {
            int m = m0 + ty * 4 + i;
            #pragma unroll
            for (int e = 0; e < NE; ++e)
                atomicAdd(&logits[(size_t)m * NE + e], part[i][e]);
        }
}

// ---------------- router + aux ----------------
__global__ __launch_bounds__(256) void router_kernel(
    const float* __restrict__ logits, const float* __restrict__ b2,
    float* __restrict__ out, float* __restrict__ acc, int M)
{
    __shared__ float s_acc[2 * NE];
    int tid = threadIdx.x;
    if (tid < 2 * NE) s_acc[tid] = 0.f;
    __syncthreads();
    int tok = blockIdx.x * blockDim.x + tid;
    if (tok < M) {
        float4 lo = *(const float4*)&logits[(size_t)tok * NE + 0];
        float4 hi = *(const float4*)&logits[(size_t)tok * NE + 4];
        float l[NE] = { lo.x + b2[0], lo.y + b2[1], lo.z + b2[2], lo.w + b2[3],
                        hi.x + b2[4], hi.y + b2[5], hi.z + b2[6], hi.w + b2[7] };
        float mx = l[0];
        #pragma unroll
        for (int e = 1; e < NE; ++e) mx = fmaxf(mx, l[e]);
        float p[NE], s = 0.f;
        #pragma unroll
        for (int e = 0; e < NE; ++e) { p[e] = __expf(l[e] - mx); s += p[e]; }
        int i1 = 0; float v1 = p[0];
        #pragma unroll
        for (int e = 1; e < NE; ++e) if (p[e] > v1) { v1 = p[e]; i1 = e; }
        int i2 = (i1 == 0) ? 1 : 0; float v2 = p[i2];
        #pragma unroll
        for (int e = 0; e < NE; ++e)
            if (e != i1 && p[e] > v2) { v2 = p[e]; i2 = e; }
        v1 /= s; v2 /= s;
        float denom = fmaxf(v1 + v2, 1e-8f);
        float o1 = v1 / denom, o2 = v2 / denom;
        float o[NE];
        #pragma unroll
        for (int e = 0; e < NE; ++e)
            o[e] = (e == i1) ? o1 : ((e == i2) ? o2 : 0.f);
        *(float4*)&out[(size_t)tok * NE + 0] = make_float4(o[0], o[1], o[2], o[3]);
        *(float4*)&out[(size_t)tok * NE + 4] = make_float4(o[4], o[5], o[6], o[7]);
        atomicAdd(&s_acc[i1], 1.f);
        atomicAdd(&s_acc[i2], 1.f);
        atomicAdd(&s_acc[NE + i1], o1);
        atomicAdd(&s_acc[NE + i2], o2);
    }
    __syncthreads();
    if (tid < 2 * NE) atomicAdd(&acc[tid], s_acc[tid]);
}

__global__ void aux_kernel(const float* __restrict__ acc,
                           float* __restrict__ out_aux, float invM)
{
    if (threadIdx.x == 0) {
        float s = 0.f;
        #pragma unroll
        for (int e = 0; e < NE; ++e)
            s += (acc[e] * invM) * (acc[NE + e] * invM);
        *out_aux = (float)NE * s;
    }
}

extern "C" void kernel_launch(void* const* d_in, const int* in_sizes, int n_in,
                              void* d_out, int out_size, void* d_ws, size_t ws_size,
                              hipStream_t stream)
{
    const float* x  = (const float*)d_in[0];
    const float* w1 = (const float*)d_in[1];
    const float* b1 = (const float*)d_in[2];
    const float* w2 = (const float*)d_in[3];
    const float* b2 = (const float*)d_in[4];

    const int MID = in_sizes[2];         // 2048
    const int H   = in_sizes[1] / MID;   // 4096
    const int M   = in_sizes[0] / H;     // 16384

    float* out = (float*)d_out;
    char* ws = (char*)d_ws;

    size_t logits_bytes = (size_t)M * NE * sizeof(float);
    float*  logits = (float*)ws;
    float*  acc    = (float*)(ws + logits_bytes);
    size_t  off_w1h = (logits_bytes + 64 + 255) & ~(size_t)255;
    size_t  w1t_bytes = (size_t)MID * H * sizeof(ushort);
    ushort* w1t_hi = (ushort*)(ws + off_w1h);
    ushort* w1t_lo = (ushort*)(ws + off_w1h + w1t_bytes);
    size_t  off_x = off_w1h + 2 * w1t_bytes;      // 256-aligned (w1t_bytes is)
    size_t  x_bytes = (size_t)M * H * sizeof(ushort);
    ushort* xh = (ushort*)(ws + off_x);
    ushort* xl = (ushort*)(ws + off_x + x_bytes);
    size_t  need_w1   = off_x;
    size_t  need_full = off_x + 2 * x_bytes;

    hipMemsetAsync(d_ws, 0, logits_bytes + 64, stream);

    const bool shape_ok = (M % BM == 0) && (MID % BN == 0) && (H % (2 * BK) == 0)
                          && ((size_t)M * H < (size_t)1 << 31);

    if (ws_size >= need_full && shape_ok) {
        dim3 gridT(MID / 32, H / 32);
        decomp_w1<<<gridT, 256, 0, stream>>>(w1, w1t_hi, w1t_lo, H, MID);
        size_t total4 = (size_t)M * H / 4;
        decomp_x<<<2048, 256, 0, stream>>>(x, xh, xl, total4);
        dim3 grid1(MID / BN, M / BM);   // N fastest -> x-strip L2 reuse
        gemm_pre<<<grid1, 256, 0, stream>>>(xh, xl, w1t_hi, w1t_lo, b1, w2,
                                            logits, M, H, MID);
    } else if (ws_size >= need_w1) {
        dim3 gridT(MID / 32, H / 32);
        decomp_w1<<<gridT, 256, 0, stream>>>(w1, w1t_hi, w1t_lo, H, MID);
        dim3 grid1(MID / BN, M / BM);
        gemm_bf16x3<<<grid1, 256, 0, stream>>>(x, w1t_hi, w1t_lo, b1, w2,
                                               logits, M, H, MID);
    } else {
        dim3 grid1(MID / TN, M / TM);
        gemm1_fused<<<grid1, 256, 0, stream>>>(x, w1, b1, w2, logits, M, H, MID);
    }

    router_kernel<<<(M + 255) / 256, 256, 0, stream>>>(logits, b2, out, acc, M);
    aux_kernel<<<1, 64, 0, stream>>>(acc, out + (size_t)M * NE, 1.0f / (float)M);
}

// Round 6
// 1548.284 us; speedup vs baseline: 1.8071x; 1.8071x over previous
//
#include <hip/hip_runtime.h>
#include <hip/hip_bf16.h>

// LayerRouter: relu(x@w1+b1)@w2 -> softmax -> top2 -> soft mask [M,8] + aux.
// M=16384, K(H)=4096, N(MID)=2048, E=8, fp32 in/out.
//
// Round 9: revert to the proven round-0/3 structure (single-buffer LDS,
// __syncthreads, in-loop A conversion, gload_lds B — best measured total)
// and remove its two measured overheads ONLY:
//  (1) v_cvt_pk_bf16_f32 (inline asm; no builtin on gfx950) for the hi/lo
//      split: 3 VALU ops/elem vs ~10 for the integer-trick RNE. Bit-identical
//      rounding -> absmax unchanged.
//  (2) both-sides LDS XOR swizzle (verified conflict-free in round 5 run):
//      B pre-swizzled at gload_lds SOURCE, A swizzled at ds_write column,
//      reads swizzled identically. Kills the 8-way ds_read_b128 conflict
//      (6.7e7 conflict-cycles in round-0 counters).
// decomp_x deleted (measured net-negative: -120us GEMM, +158us pass).

#define NE 8
#define BM 128
#define BN 128
#define BK 32

typedef __attribute__((ext_vector_type(8))) short bf16x8;
typedef __attribute__((ext_vector_type(4))) float f32x4;

__device__ inline ushort f2bf_rne(float v) {
    unsigned x = __float_as_uint(v);
    unsigned r = (x + 0x7fffu + ((x >> 16) & 1u)) >> 16;
    return (ushort)r;
}
__device__ inline float bf2f(ushort u) {
    return __uint_as_float(((unsigned)u) << 16);
}

// packed RNE f32x2 -> bf16x2 (word0 = cvt(a), word1 = cvt(b))
__device__ inline unsigned cvtpk(float a, float b) {
    unsigned r;
    asm("v_cvt_pk_bf16_f32 %0, %1, %2" : "=v"(r) : "v"(a), "v"(b));
    return r;
}

#define GLL16(gp, lp) __builtin_amdgcn_global_load_lds( \
    (const __attribute__((address_space(1))) unsigned*)(gp), \
    (__attribute__((address_space(3))) unsigned*)(lp), 16, 0, 0)

#define MFMA16(a, b, c) __builtin_amdgcn_mfma_f32_16x16x32_bf16((a), (b), (c), 0, 0, 0)

// ---------------- w1 [K][N] fp32 -> w1t_hi/lo [N][K] bf16 ----------------
__global__ __launch_bounds__(256) void decomp_w1(
    const float* __restrict__ w1, ushort* __restrict__ w1t_hi,
    ushort* __restrict__ w1t_lo, int K, int N)
{
    __shared__ float tile[32][33];
    const int k0 = blockIdx.y * 32, n0 = blockIdx.x * 32;
    const int t = threadIdx.x;
    {
        int k = t >> 3, n4 = (t & 7) * 4;
        float4 v = *(const float4*)&w1[(size_t)(k0 + k) * N + n0 + n4];
        tile[k][n4 + 0] = v.x; tile[k][n4 + 1] = v.y;
        tile[k][n4 + 2] = v.z; tile[k][n4 + 3] = v.w;
    }
    __syncthreads();
    {
        int n = t >> 3, k4 = (t & 7) * 4;
        ushort4 h, l;
        float v;
        v = tile[k4 + 0][n]; h.x = f2bf_rne(v); l.x = f2bf_rne(v - bf2f(h.x));
        v = tile[k4 + 1][n]; h.y = f2bf_rne(v); l.y = f2bf_rne(v - bf2f(h.y));
        v = tile[k4 + 2][n]; h.z = f2bf_rne(v); l.z = f2bf_rne(v - bf2f(h.z));
        v = tile[k4 + 3][n]; h.w = f2bf_rne(v); l.w = f2bf_rne(v - bf2f(h.w));
        *(ushort4*)&w1t_hi[(size_t)(n0 + n) * K + k0 + k4] = h;
        *(ushort4*)&w1t_lo[(size_t)(n0 + n) * K + k0 + k4] = l;
    }
}

// ---- bf16x3 MFMA GEMM: round-0 structure + cvt_pk conversion + swizzle --
__global__ __launch_bounds__(256) void gemm_fused(
    const float* __restrict__ x,        // [M][K] fp32
    const ushort* __restrict__ w1t_hi,  // [N][K]
    const ushort* __restrict__ w1t_lo,  // [N][K]
    const float* __restrict__ b1,       // [N]
    const float* __restrict__ w2,       // [N][NE]
    float* __restrict__ logits,         // [M][NE] atomic accumulate
    int M, int K, int N)
{
    __shared__ __align__(16) ushort Ah[BM][BK], Al[BM][BK];   // 8 KB each
    __shared__ __align__(16) ushort Bh[BN][BK], Bl[BN][BK];   // 8 KB each

    const int t    = threadIdx.x;
    const int lane = t & 63, wave = t >> 6;
    const int wm   = wave >> 1, wn = wave & 1;
    const int quad = lane >> 4, l15 = lane & 15;
    const int n0   = blockIdx.x * BN;   // N fastest: 16 n-blocks share x strip
    const int m0   = blockIdx.y * BM;

    // ---- A staging (fp32 -> reg -> cvt_pk split -> swizzled ds_write) ----
    // thread t, pass p: reads float4 x[m0+am+32p][k0+ak..+3].
    // Swizzled write column: group (ak>>3) XOR ((row>>1)&3); row = am+32p and
    // (32p>>1)&3 == 0, so the key is p-invariant: (am>>1)&3.
    const int am = t >> 3, ak = (t & 7) * 4;
    const int ak_s = ((((ak >> 3) ^ ((am >> 1) & 3)) << 3) | (ak & 4));
    const float* xg = &x[(size_t)(m0 + am) * K + ak];

    // ---- B staging via global_load_lds, PRE-SWIZZLED global source ------
    // chunk c (16B) -> LDS byte c*16 (linear); covers row c>>2, global
    // k-group ((c&3) ^ ((c>>3)&3)). Read-side XOR recovers it.
    const int c0 = wave * 64 + lane;          // == t
    const int c1 = c0 + 256;
    const int gk0 = ((c0 & 3) ^ ((c0 >> 3) & 3)) * 8;
    const int gk1 = ((c1 & 3) ^ ((c1 >> 3) & 3)) * 8;
    const size_t bg0 = (size_t)(n0 + (c0 >> 2)) * K + gk0;
    const size_t bg1 = (size_t)(n0 + (c1 >> 2)) * K + gk1;
    ushort* const bh_base  = &Bh[0][0] + (size_t)(wave * 64) * 8;
    ushort* const bh_base1 = &Bh[0][0] + (size_t)(wave * 64 + 256) * 8;
    ushort* const bl_base  = &Bl[0][0] + (size_t)(wave * 64) * 8;
    ushort* const bl_base1 = &Bl[0][0] + (size_t)(wave * 64 + 256) * 8;

    // read-side swizzled column (A and B identical mapping)
    const int col = (quad ^ ((l15 >> 1) & 3)) * 8;

    f32x4 acc[4][4] = {};

    for (int k0 = 0; k0 < K; k0 += BK) {
        __syncthreads();
        GLL16(w1t_hi + bg0 + k0, bh_base);
        GLL16(w1t_hi + bg1 + k0, bh_base1);
        GLL16(w1t_lo + bg0 + k0, bl_base);
        GLL16(w1t_lo + bg1 + k0, bl_base1);
        #pragma unroll
        for (int p = 0; p < 4; ++p) {
            float4 v = *(const float4*)(xg + (size_t)p * 32 * K + k0);
            // hi via packed RNE cvt (word0 = first arg)
            unsigned h01 = cvtpk(v.x, v.y);
            unsigned h23 = cvtpk(v.z, v.w);
            // residuals vs EXACT bf2f(hi) extracted from the packed words
            float rx = v.x - __uint_as_float(h01 << 16);
            float ry = v.y - __uint_as_float(h01 & 0xffff0000u);
            float rz = v.z - __uint_as_float(h23 << 16);
            float rw = v.w - __uint_as_float(h23 & 0xffff0000u);
            unsigned l01 = cvtpk(rx, ry);
            unsigned l23 = cvtpk(rz, rw);
            uint2 hv = make_uint2(h01, h23), lv = make_uint2(l01, l23);
            *(uint2*)&Ah[am + 32 * p][ak_s] = hv;
            *(uint2*)&Al[am + 32 * p][ak_s] = lv;
        }
        __syncthreads();

        bf16x8 afh[4], afl[4], bfh[4], bfl[4];
        #pragma unroll
        for (int i = 0; i < 4; ++i) {
            afh[i] = *(const bf16x8*)&Ah[wm * 64 + i * 16 + l15][col];
            afl[i] = *(const bf16x8*)&Al[wm * 64 + i * 16 + l15][col];
        }
        #pragma unroll
        for (int j = 0; j < 4; ++j) {
            bfh[j] = *(const bf16x8*)&Bh[wn * 64 + j * 16 + l15][col];
            bfl[j] = *(const bf16x8*)&Bl[wn * 64 + j * 16 + l15][col];
        }
        #pragma unroll
        for (int i = 0; i < 4; ++i)
            #pragma unroll
            for (int j = 0; j < 4; ++j) {
                acc[i][j] = MFMA16(afh[i], bfh[j], acc[i][j]);
                acc[i][j] = MFMA16(afh[i], bfl[j], acc[i][j]);
                acc[i][j] = MFMA16(afl[i], bfh[j], acc[i][j]);
            }
    }

    // ---- epilogue: h = relu(acc + b1); logits += h @ w2 ----
    // acc[i][j][r]: row = m0+wm*64+i*16+quad*4+r, col = n0+wn*64+j*16+l15
    float w2row[4][NE], b1v[4];
    #pragma unroll
    for (int j = 0; j < 4; ++j) {
        int n = n0 + wn * 64 + j * 16 + l15;
        b1v[j] = b1[n];
        float4 lo4 = *(const float4*)&w2[(size_t)n * NE + 0];
        float4 hi4 = *(const float4*)&w2[(size_t)n * NE + 4];
        w2row[j][0] = lo4.x; w2row[j][1] = lo4.y; w2row[j][2] = lo4.z; w2row[j][3] = lo4.w;
        w2row[j][4] = hi4.x; w2row[j][5] = hi4.y; w2row[j][6] = hi4.z; w2row[j][7] = hi4.w;
    }
    #pragma unroll
    for (int i = 0; i < 4; ++i) {
        #pragma unroll
        for (int r = 0; r < 4; ++r) {
            float s[NE];
            #pragma unroll
            for (int e = 0; e < NE; ++e) s[e] = 0.f;
            #pragma unroll
            for (int j = 0; j < 4; ++j) {
                float h = acc[i][j][r] + b1v[j];
                h = h > 0.f ? h : 0.f;
                #pragma unroll
                for (int e = 0; e < NE; ++e) s[e] = fmaf(h, w2row[j][e], s[e]);
            }
            #pragma unroll
            for (int e = 0; e < NE; ++e) {
                #pragma unroll
                for (int off = 8; off > 0; off >>= 1)
                    s[e] += __shfl_down(s[e], off, 16);
            }
            if (l15 == 0) {
                int m = m0 + wm * 64 + i * 16 + quad * 4 + r;
                #pragma unroll
                for (int e = 0; e < NE; ++e)
                    atomicAdd(&logits[(size_t)m * NE + e], s[e]);
            }
        }
    }
}

// ---------------- fp32 fallback GEMM (ws-size guard) ----------------
#define TM 64
#define TN 64
#define FBK 16

__global__ __launch_bounds__(256) void gemm1_fused(
    const float* __restrict__ x, const float* __restrict__ w1,
    const float* __restrict__ b1, const float* __restrict__ w2,
    float* __restrict__ logits, int M, int K, int N)
{
    __shared__ float As[FBK][TM + 4];
    __shared__ float Bs[FBK][TN];
    const int tid = threadIdx.x;
    const int tx = tid & 15, ty = tid >> 4;
    const int n0 = blockIdx.x * TN, m0 = blockIdx.y * TM;
    const int a_k = tid & 15, a_r = tid >> 4;
    const int b_n = tid & 63, b_k = tid >> 6;
    float acc[4][4] = {};
    for (int k0 = 0; k0 < K; k0 += FBK) {
        #pragma unroll
        for (int p = 0; p < 4; ++p) {
            int r = a_r + 16 * p;
            As[a_k][r] = x[(size_t)(m0 + r) * K + (k0 + a_k)];
        }
        #pragma unroll
        for (int p = 0; p < 4; ++p) {
            int k = b_k + 4 * p;
            Bs[k][b_n] = w1[(size_t)(k0 + k) * N + (n0 + b_n)];
        }
        __syncthreads();
        #pragma unroll
        for (int k = 0; k < FBK; ++k) {
            float a[4], b[4];
            #pragma unroll
            for (int i = 0; i < 4; ++i) a[i] = As[k][ty * 4 + i];
            #pragma unroll
            for (int j = 0; j < 4; ++j) b[j] = Bs[k][tx * 4 + j];
            #pragma unroll
            for (int i = 0; i < 4; ++i)
                #pragma unroll
                for (int j = 0; j < 4; ++j)
                    acc[i][j] = fmaf(a[i], b[j], acc[i][j]);
        }
        __syncthreads();
    }
    float part[4][NE];
    #pragma unroll
    for (int i = 0; i < 4; ++i)
        #pragma unroll
        for (int e = 0; e < NE; ++e) part[i][e] = 0.f;
    #pragma unroll
    for (int j = 0; j < 4; ++j) {
        int n = n0 + tx * 4 + j;
        float bias = b1[n];
        float4 wlo = *(const float4*)&w2[(size_t)n * NE + 0];
        float4 whi = *(const float4*)&w2[(size_t)n * NE + 4];
        #pragma unroll
        for (int i = 0; i < 4; ++i) {
            float h = acc[i][j] + bias;
            h = h > 0.f ? h : 0.f;
            part[i][0] = fmaf(h, wlo.x, part[i][0]);
            part[i][1] = fmaf(h, wlo.y, part[i][1]);
            part[i][2] = fmaf(h, wlo.z, part[i][2]);
            part[i][3] = fmaf(h, wlo.w, part[i][3]);
            part[i][4] = fmaf(h, whi.x, part[i][4]);
            part[i][5] = fmaf(h, whi.y, part[i][5]);
            part[i][6] = fmaf(h, whi.z, part[i][6]);
            part[i][7] = fmaf(h, whi.w, part[i][7]);
        }
    }
    #pragma unroll
    for (int i = 0; i < 4; ++i)
        #pragma unroll
        for (int e = 0; e < NE; ++e) {
            float v = part[i][e];
            #pragma unroll
            for (int off = 8; off > 0; off >>= 1) v += __shfl_down(v, off, 16);
            part[i][e] = v;
        }
    if (tx == 0)
        #pragma unroll
        for (int i = 0; i < 4; ++i) {
            int m = m0 + ty * 4 + i;
            #pragma unroll
            for (int e = 0; e < NE; ++e)
                atomicAdd(&logits[(size_t)m * NE + e], part[i][e]);
        }
}

// ---------------- router + aux ----------------
__global__ __launch_bounds__(256) void router_kernel(
    const float* __restrict__ logits, const float* __restrict__ b2,
    float* __restrict__ out, float* __restrict__ acc, int M)
{
    __shared__ float s_acc[2 * NE];
    int tid = threadIdx.x;
    if (tid < 2 * NE) s_acc[tid] = 0.f;
    __syncthreads();
    int tok = blockIdx.x * blockDim.x + tid;
    if (tok < M) {
        float4 lo = *(const float4*)&logits[(size_t)tok * NE + 0];
        float4 hi = *(const float4*)&logits[(size_t)tok * NE + 4];
        float l[NE] = { lo.x + b2[0], lo.y + b2[1], lo.z + b2[2], lo.w + b2[3],
                        hi.x + b2[4], hi.y + b2[5], hi.z + b2[6], hi.w + b2[7] };
        float mx = l[0];
        #pragma unroll
        for (int e = 1; e < NE; ++e) mx = fmaxf(mx, l[e]);
        float p[NE], s = 0.f;
        #pragma unroll
        for (int e = 0; e < NE; ++e) { p[e] = __expf(l[e] - mx); s += p[e]; }
        int i1 = 0; float v1 = p[0];
        #pragma unroll
        for (int e = 1; e < NE; ++e) if (p[e] > v1) { v1 = p[e]; i1 = e; }
        int i2 = (i1 == 0) ? 1 : 0; float v2 = p[i2];
        #pragma unroll
        for (int e = 0; e < NE; ++e)
            if (e != i1 && p[e] > v2) { v2 = p[e]; i2 = e; }
        v1 /= s; v2 /= s;
        float denom = fmaxf(v1 + v2, 1e-8f);
        float o1 = v1 / denom, o2 = v2 / denom;
        float o[NE];
        #pragma unroll
        for (int e = 0; e < NE; ++e)
            o[e] = (e == i1) ? o1 : ((e == i2) ? o2 : 0.f);
        *(float4*)&out[(size_t)tok * NE + 0] = make_float4(o[0], o[1], o[2], o[3]);
        *(float4*)&out[(size_t)tok * NE + 4] = make_float4(o[4], o[5], o[6], o[7]);
        atomicAdd(&s_acc[i1], 1.f);
        atomicAdd(&s_acc[i2], 1.f);
        atomicAdd(&s_acc[NE + i1], o1);
        atomicAdd(&s_acc[NE + i2], o2);
    }
    __syncthreads();
    if (tid < 2 * NE) atomicAdd(&acc[tid], s_acc[tid]);
}

__global__ void aux_kernel(const float* __restrict__ acc,
                           float* __restrict__ out_aux, float invM)
{
    if (threadIdx.x == 0) {
        float s = 0.f;
        #pragma unroll
        for (int e = 0; e < NE; ++e)
            s += (acc[e] * invM) * (acc[NE + e] * invM);
        *out_aux = (float)NE * s;
    }
}

extern "C" void kernel_launch(void* const* d_in, const int* in_sizes, int n_in,
                              void* d_out, int out_size, void* d_ws, size_t ws_size,
                              hipStream_t stream)
{
    const float* x  = (const float*)d_in[0];
    const float* w1 = (const float*)d_in[1];
    const float* b1 = (const float*)d_in[2];
    const float* w2 = (const float*)d_in[3];
    const float* b2 = (const float*)d_in[4];

    const int MID = in_sizes[2];         // 2048
    const int H   = in_sizes[1] / MID;   // 4096
    const int M   = in_sizes[0] / H;     // 16384

    float* out = (float*)d_out;
    char* ws = (char*)d_ws;

    size_t logits_bytes = (size_t)M * NE * sizeof(float);
    float*  logits = (float*)ws;
    float*  acc    = (float*)(ws + logits_bytes);
    size_t  off_w1h = (logits_bytes + 64 + 255) & ~(size_t)255;
    size_t  w1t_bytes = (size_t)MID * H * sizeof(ushort);
    ushort* w1t_hi = (ushort*)(ws + off_w1h);
    ushort* w1t_lo = (ushort*)(ws + off_w1h + w1t_bytes);
    size_t  need_w1 = off_w1h + 2 * w1t_bytes;

    hipMemsetAsync(d_ws, 0, logits_bytes + 64, stream);

    const bool shape_ok = (M % BM == 0) && (MID % BN == 0) && (H % BK == 0)
                          && (H % 32 == 0) && (MID % 32 == 0);

    if (ws_size >= need_w1 && shape_ok) {
        dim3 gridT(MID / 32, H / 32);
        decomp_w1<<<gridT, 256, 0, stream>>>(w1, w1t_hi, w1t_lo, H, MID);
        dim3 grid1(MID / BN, M / BM);   // N fastest -> x-strip L2 reuse
        gemm_fused<<<grid1, 256, 0, stream>>>(x, w1t_hi, w1t_lo, b1, w2,
                                              logits, M, H, MID);
    } else {
        dim3 grid1(MID / TN, M / TM);
        gemm1_fused<<<grid1, 256, 0, stream>>>(x, w1, b1, w2, logits, M, H, MID);
    }

    router_kernel<<<(M + 255) / 256, 256, 0, stream>>>(logits, b2, out, acc, M);
    aux_kernel<<<1, 64, 0, stream>>>(acc, out + (size_t)M * NE, 1.0f / (float)M);
}

// Round 7
// 1359.674 us; speedup vs baseline: 2.0578x; 1.1387x over previous
//
#include <hip/hip_runtime.h>
#include <hip/hip_bf16.h>

// LayerRouter: relu(x@w1+b1)@w2 -> softmax -> top2 -> soft mask [M,8] + aux.
// M=16384, K(H)=4096, N(MID)=2048, E=8, fp32 in/out.
//
// Round 10: r6 structure with the critical path de-latencied:
//  - x prefetched to REGISTERS one K-tile ahead (xrA/xrB, static names):
//    convert phase is pure VALU+ds_write, no global latency exposed.
//  - B double-buffered (LDS 48KB total -> 2-3 blocks/CU) via gload_lds,
//    issued one tile ahead; counted s_waitcnt vmcnt(4), NEVER 0 in-loop.
//  - Race-clean cadence: buffers written only after the barrier that
//    retires their readers (reads are MFMA-consumed pre-barrier);
//    lgkmcnt(0) drains own ds_writes before publish. NO sched_barrier,
//    no forced read serialization (r4 lesson) -> compiler keeps its fine
//    ds_read/MFMA interleave.
// Numerics (cvt_pk split, MFMA order, swizzles, epilogue) identical to r6.

#define NE 8
#define BM 128
#define BN 128
#define BK 32

typedef __attribute__((ext_vector_type(8))) short bf16x8;
typedef __attribute__((ext_vector_type(4))) float f32x4;

__device__ inline ushort f2bf_rne(float v) {
    unsigned x = __float_as_uint(v);
    unsigned r = (x + 0x7fffu + ((x >> 16) & 1u)) >> 16;
    return (ushort)r;
}
__device__ inline float bf2f(ushort u) {
    return __uint_as_float(((unsigned)u) << 16);
}

// packed RNE f32x2 -> bf16x2 (low16 = cvt(a), high16 = cvt(b))
__device__ inline unsigned cvtpk(float a, float b) {
    unsigned r;
    asm("v_cvt_pk_bf16_f32 %0, %1, %2" : "=v"(r) : "v"(a), "v"(b));
    return r;
}

#define GLL16(gp, lp) __builtin_amdgcn_global_load_lds( \
    (const __attribute__((address_space(1))) unsigned*)(gp), \
    (__attribute__((address_space(3))) unsigned*)(lp), 16, 0, 0)

// compiler-fence + HW barrier (raw s_barrier is NOT a compiler memory fence)
#define BARRIER() do { asm volatile("" ::: "memory"); \
    __builtin_amdgcn_s_barrier(); \
    asm volatile("" ::: "memory"); } while (0)

#define MFMA16(a, b, c) __builtin_amdgcn_mfma_f32_16x16x32_bf16((a), (b), (c), 0, 0, 0)

// ---------------- w1 [K][N] fp32 -> w1t_hi/lo [N][K] bf16 ----------------
__global__ __launch_bounds__(256) void decomp_w1(
    const float* __restrict__ w1, ushort* __restrict__ w1t_hi,
    ushort* __restrict__ w1t_lo, int K, int N)
{
    __shared__ float tile[32][33];
    const int k0 = blockIdx.y * 32, n0 = blockIdx.x * 32;
    const int t = threadIdx.x;
    {
        int k = t >> 3, n4 = (t & 7) * 4;
        float4 v = *(const float4*)&w1[(size_t)(k0 + k) * N + n0 + n4];
        tile[k][n4 + 0] = v.x; tile[k][n4 + 1] = v.y;
        tile[k][n4 + 2] = v.z; tile[k][n4 + 3] = v.w;
    }
    __syncthreads();
    {
        int n = t >> 3, k4 = (t & 7) * 4;
        ushort4 h, l;
        float v;
        v = tile[k4 + 0][n]; h.x = f2bf_rne(v); l.x = f2bf_rne(v - bf2f(h.x));
        v = tile[k4 + 1][n]; h.y = f2bf_rne(v); l.y = f2bf_rne(v - bf2f(h.y));
        v = tile[k4 + 2][n]; h.z = f2bf_rne(v); l.z = f2bf_rne(v - bf2f(h.z));
        v = tile[k4 + 3][n]; h.w = f2bf_rne(v); l.w = f2bf_rne(v - bf2f(h.w));
        *(ushort4*)&w1t_hi[(size_t)(n0 + n) * K + k0 + k4] = h;
        *(ushort4*)&w1t_lo[(size_t)(n0 + n) * K + k0 + k4] = l;
    }
}

// ---- bf16x3 MFMA GEMM: reg-prefetch A, dbuf B, counted vmcnt ------------
__global__ __launch_bounds__(256, 2) void gemm_fused(
    const float* __restrict__ x,        // [M][K] fp32
    const ushort* __restrict__ w1t_hi,  // [N][K]
    const ushort* __restrict__ w1t_lo,  // [N][K]
    const float* __restrict__ b1,       // [N]
    const float* __restrict__ w2,       // [N][NE]
    float* __restrict__ logits,         // [M][NE] atomic accumulate
    int M, int K, int N)
{
    __shared__ __align__(16) ushort Ah[BM][BK], Al[BM][BK];        // 8+8 KB
    __shared__ __align__(16) ushort Bh[2][BN][BK], Bl[2][BN][BK];  // 16+16 KB

    const int t    = threadIdx.x;
    const int lane = t & 63, wave = t >> 6;
    const int wm   = wave >> 1, wn = wave & 1;
    const int quad = lane >> 4, l15 = lane & 15;
    const int n0   = blockIdx.x * BN;   // N fastest: 16 n-blocks share x strip
    const int m0   = blockIdx.y * BM;

    // A staging map (thread t, pass p reads float4 x[m0+am+32p][.]) with
    // swizzled ds_write column; key (am>>1)&3 is p-invariant (r6-verified).
    const int am = t >> 3, ak = (t & 7) * 4;
    const int ak_s = ((((ak >> 3) ^ ((am >> 1) & 3)) << 3) | (ak & 4));
    const float* xg = &x[(size_t)(m0 + am) * K + ak];

    // B staging via gload_lds, PRE-SWIZZLED global source (r6-verified).
    const int c0 = t, c1 = t + 256;
    const int gk0 = ((c0 & 3) ^ ((c0 >> 3) & 3)) * 8;
    const int gk1 = ((c1 & 3) ^ ((c1 >> 3) & 3)) * 8;
    const size_t bg0 = (size_t)(n0 + (c0 >> 2)) * K + gk0;
    const size_t bg1 = (size_t)(n0 + (c1 >> 2)) * K + gk1;
    const int stq0 = (wave * 64) * 8;          // ushort offsets
    const int stq1 = (wave * 64 + 256) * 8;

    const int col = (quad ^ ((l15 >> 1) & 3)) * 8;   // read-side swizzle

    f32x4 acc[4][4] = {};

    auto BSTAGE = [&](int nb, int koff) {      // 4 gload_lds
        GLL16(w1t_hi + bg0 + koff, &Bh[nb][0][0] + stq0);
        GLL16(w1t_hi + bg1 + koff, &Bh[nb][0][0] + stq1);
        GLL16(w1t_lo + bg0 + koff, &Bl[nb][0][0] + stq0);
        GLL16(w1t_lo + bg1 + koff, &Bl[nb][0][0] + stq1);
    };
    auto XLOAD = [&](float4 (&xr)[4], int koff) {   // 4 dwordx4 -> regs
        #pragma unroll
        for (int p = 0; p < 4; ++p)
            xr[p] = *(const float4*)(xg + (size_t)p * 32 * K + koff);
    };
    auto AWRITE = [&](const float4 (&xr)[4]) {      // cvt_pk split + ds_write
        #pragma unroll
        for (int p = 0; p < 4; ++p) {
            float4 v = xr[p];
            unsigned h01 = cvtpk(v.x, v.y);
            unsigned h23 = cvtpk(v.z, v.w);
            float rx = v.x - __uint_as_float(h01 << 16);
            float ry = v.y - __uint_as_float(h01 & 0xffff0000u);
            float rz = v.z - __uint_as_float(h23 << 16);
            float rw = v.w - __uint_as_float(h23 & 0xffff0000u);
            unsigned l01 = cvtpk(rx, ry);
            unsigned l23 = cvtpk(rz, rw);
            *(uint2*)&Ah[am + 32 * p][ak_s] = make_uint2(h01, h23);
            *(uint2*)&Al[am + 32 * p][ak_s] = make_uint2(l01, l23);
        }
    };
    auto COMPUTE = [&](int nb) {
        bf16x8 afh[4], afl[4], bfh[4], bfl[4];
        #pragma unroll
        for (int i = 0; i < 4; ++i) {
            afh[i] = *(const bf16x8*)&Ah[wm * 64 + i * 16 + l15][col];
            afl[i] = *(const bf16x8*)&Al[wm * 64 + i * 16 + l15][col];
        }
        #pragma unroll
        for (int j = 0; j < 4; ++j) {
            bfh[j] = *(const bf16x8*)&Bh[nb][wn * 64 + j * 16 + l15][col];
            bfl[j] = *(const bf16x8*)&Bl[nb][wn * 64 + j * 16 + l15][col];
        }
        #pragma unroll
        for (int i = 0; i < 4; ++i)
            #pragma unroll
            for (int j = 0; j < 4; ++j) {
                acc[i][j] = MFMA16(afh[i], bfh[j], acc[i][j]);
                acc[i][j] = MFMA16(afh[i], bfl[j], acc[i][j]);
                acc[i][j] = MFMA16(afl[i], bfh[j], acc[i][j]);
            }
    };

    const int NT = K / BK;                     // 128, even
    float4 xrA[4], xrB[4];

    XLOAD(xrA, 0);
    BSTAGE(0, 0);                              // 8 ops in flight

    for (int T = 0; T < NT; T += 2) {
        // ---- step A: tile T (xrA, B buf0) ----
        XLOAD(xrB, (T + 1) * BK);              // T+1 <= NT-1 always (NT even)
        asm volatile("s_waitcnt vmcnt(4)" ::: "memory");  // xrA+buf0 landed
        BARRIER();          // retires readers of A(T-1) and buf1(T-1); buf0 published
        BSTAGE(1, (T + 1) * BK);               // buf1 readers retired -> safe
        AWRITE(xrA);                           // A readers retired -> safe
        asm volatile("s_waitcnt lgkmcnt(0)" ::: "memory"); // my ds_writes done
        BARRIER();          // A(T) published
        COMPUTE(0);
        // ---- step B: tile T+1 (xrB, B buf1) ----
        if (T + 2 < NT) {
            XLOAD(xrA, (T + 2) * BK);
            asm volatile("s_waitcnt vmcnt(4)" ::: "memory"); // xrB+buf1 landed
        } else {
            asm volatile("s_waitcnt vmcnt(0)" ::: "memory");
        }
        BARRIER();          // retires readers of A(T) and buf0(T); buf1 published
        if (T + 2 < NT) BSTAGE(0, (T + 2) * BK);
        AWRITE(xrB);
        asm volatile("s_waitcnt lgkmcnt(0)" ::: "memory");
        BARRIER();          // A(T+1) published
        COMPUTE(1);
    }

    // ---- epilogue: h = relu(acc + b1); logits += h @ w2 ----
    // acc[i][j][r]: row = m0+wm*64+i*16+quad*4+r, col = n0+wn*64+j*16+l15
    float w2row[4][NE], b1v[4];
    #pragma unroll
    for (int j = 0; j < 4; ++j) {
        int n = n0 + wn * 64 + j * 16 + l15;
        b1v[j] = b1[n];
        float4 lo4 = *(const float4*)&w2[(size_t)n * NE + 0];
        float4 hi4 = *(const float4*)&w2[(size_t)n * NE + 4];
        w2row[j][0] = lo4.x; w2row[j][1] = lo4.y; w2row[j][2] = lo4.z; w2row[j][3] = lo4.w;
        w2row[j][4] = hi4.x; w2row[j][5] = hi4.y; w2row[j][6] = hi4.z; w2row[j][7] = hi4.w;
    }
    #pragma unroll
    for (int i = 0; i < 4; ++i) {
        #pragma unroll
        for (int r = 0; r < 4; ++r) {
            float s[NE];
            #pragma unroll
            for (int e = 0; e < NE; ++e) s[e] = 0.f;
            #pragma unroll
            for (int j = 0; j < 4; ++j) {
                float h = acc[i][j][r] + b1v[j];
                h = h > 0.f ? h : 0.f;
                #pragma unroll
                for (int e = 0; e < NE; ++e) s[e] = fmaf(h, w2row[j][e], s[e]);
            }
            #pragma unroll
            for (int e = 0; e < NE; ++e) {
                #pragma unroll
                for (int off = 8; off > 0; off >>= 1)
                    s[e] += __shfl_down(s[e], off, 16);
            }
            if (l15 == 0) {
                int m = m0 + wm * 64 + i * 16 + quad * 4 + r;
                #pragma unroll
                for (int e = 0; e < NE; ++e)
                    atomicAdd(&logits[(size_t)m * NE + e], s[e]);
            }
        }
    }
}

// ---------------- fp32 fallback GEMM (ws-size guard) ----------------
#define TM 64
#define TN 64
#define FBK 16

__global__ __launch_bounds__(256) void gemm1_fused(
    const float* __restrict__ x, const float* __restrict__ w1,
    const float* __restrict__ b1, const float* __restrict__ w2,
    float* __restrict__ logits, int M, int K, int N)
{
    __shared__ float As[FBK][TM + 4];
    __shared__ float Bs[FBK][TN];
    const int tid = threadIdx.x;
    const int tx = tid & 15, ty = tid >> 4;
    const int n0 = blockIdx.x * TN, m0 = blockIdx.y * TM;
    const int a_k = tid & 15, a_r = tid >> 4;
    const int b_n = tid & 63, b_k = tid >> 6;
    float acc[4][4] = {};
    for (int k0 = 0; k0 < K; k0 += FBK) {
        #pragma unroll
        for (int p = 0; p < 4; ++p) {
            int r = a_r + 16 * p;
            As[a_k][r] = x[(size_t)(m0 + r) * K + (k0 + a_k)];
        }
        #pragma unroll
        for (int p = 0; p < 4; ++p) {
            int k = b_k + 4 * p;
            Bs[k][b_n] = w1[(size_t)(k0 + k) * N + (n0 + b_n)];
        }
        __syncthreads();
        #pragma unroll
        for (int k = 0; k < FBK; ++k) {
            float a[4], b[4];
            #pragma unroll
            for (int i = 0; i < 4; ++i) a[i] = As[k][ty * 4 + i];
            #pragma unroll
            for (int j = 0; j < 4; ++j) b[j] = Bs[k][tx * 4 + j];
            #pragma unroll
            for (int i = 0; i < 4; ++i)
                #pragma unroll
                for (int j = 0; j < 4; ++j)
                    acc[i][j] = fmaf(a[i], b[j], acc[i][j]);
        }
        __syncthreads();
    }
    float part[4][NE];
    #pragma unroll
    for (int i = 0; i < 4; ++i)
        #pragma unroll
        for (int e = 0; e < NE; ++e) part[i][e] = 0.f;
    #pragma unroll
    for (int j = 0; j < 4; ++j) {
        int n = n0 + tx * 4 + j;
        float bias = b1[n];
        float4 wlo = *(const float4*)&w2[(size_t)n * NE + 0];
        float4 whi = *(const float4*)&w2[(size_t)n * NE + 4];
        #pragma unroll
        for (int i = 0; i < 4; ++i) {
            float h = acc[i][j] + bias;
            h = h > 0.f ? h : 0.f;
            part[i][0] = fmaf(h, wlo.x, part[i][0]);
            part[i][1] = fmaf(h, wlo.y, part[i][1]);
            part[i][2] = fmaf(h, wlo.z, part[i][2]);
            part[i][3] = fmaf(h, wlo.w, part[i][3]);
            part[i][4] = fmaf(h, whi.x, part[i][4]);
            part[i][5] = fmaf(h, whi.y, part[i][5]);
            part[i][6] = fmaf(h, whi.z, part[i][6]);
            part[i][7] = fmaf(h, whi.w, part[i][7]);
        }
    }
    #pragma unroll
    for (int i = 0; i < 4; ++i)
        #pragma unroll
        for (int e = 0; e < NE; ++e) {
            float v = part[i][e];
            #pragma unroll
            for (int off = 8; off > 0; off >>= 1) v += __shfl_down(v, off, 16);
            part[i][e] = v;
        }
    if (tx == 0)
        #pragma unroll
        for (int i = 0; i < 4; ++i) {
            int m = m0 + ty * 4 + i;
            #pragma unroll
            for (int e = 0; e < NE; ++e)
                atomicAdd(&logits[(size_t)m * NE + e], part[i][e]);
        }
}

// ---------------- router + aux ----------------
__global__ __launch_bounds__(256) void router_kernel(
    const float* __restrict__ logits, const float* __restrict__ b2,
    float* __restrict__ out, float* __restrict__ acc, int M)
{
    __shared__ float s_acc[2 * NE];
    int tid = threadIdx.x;
    if (tid < 2 * NE) s_acc[tid] = 0.f;
    __syncthreads();
    int tok = blockIdx.x * blockDim.x + tid;
    if (tok < M) {
        float4 lo = *(const float4*)&logits[(size_t)tok * NE + 0];
        float4 hi = *(const float4*)&logits[(size_t)tok * NE + 4];
        float l[NE] = { lo.x + b2[0], lo.y + b2[1], lo.z + b2[2], lo.w + b2[3],
                        hi.x + b2[4], hi.y + b2[5], hi.z + b2[6], hi.w + b2[7] };
        float mx = l[0];
        #pragma unroll
        for (int e = 1; e < NE; ++e) mx = fmaxf(mx, l[e]);
        float p[NE], s = 0.f;
        #pragma unroll
        for (int e = 0; e < NE; ++e) { p[e] = __expf(l[e] - mx); s += p[e]; }
        int i1 = 0; float v1 = p[0];
        #pragma unroll
        for (int e = 1; e < NE; ++e) if (p[e] > v1) { v1 = p[e]; i1 = e; }
        int i2 = (i1 == 0) ? 1 : 0; float v2 = p[i2];
        #pragma unroll
        for (int e = 0; e < NE; ++e)
            if (e != i1 && p[e] > v2) { v2 = p[e]; i2 = e; }
        v1 /= s; v2 /= s;
        float denom = fmaxf(v1 + v2, 1e-8f);
        float o1 = v1 / denom, o2 = v2 / denom;
        float o[NE];
        #pragma unroll
        for (int e = 0; e < NE; ++e)
            o[e] = (e == i1) ? o1 : ((e == i2) ? o2 : 0.f);
        *(float4*)&out[(size_t)tok * NE + 0] = make_float4(o[0], o[1], o[2], o[3]);
        *(float4*)&out[(size_t)tok * NE + 4] = make_float4(o[4], o[5], o[6], o[7]);
        atomicAdd(&s_acc[i1], 1.f);
        atomicAdd(&s_acc[i2], 1.f);
        atomicAdd(&s_acc[NE + i1], o1);
        atomicAdd(&s_acc[NE + i2], o2);
    }
    __syncthreads();
    if (tid < 2 * NE) atomicAdd(&acc[tid], s_acc[tid]);
}

__global__ void aux_kernel(const float* __restrict__ acc,
                           float* __restrict__ out_aux, float invM)
{
    if (threadIdx.x == 0) {
        float s = 0.f;
        #pragma unroll
        for (int e = 0; e < NE; ++e)
            s += (acc[e] * invM) * (acc[NE + e] * invM);
        *out_aux = (float)NE * s;
    }
}

extern "C" void kernel_launch(void* const* d_in, const int* in_sizes, int n_in,
                              void* d_out, int out_size, void* d_ws, size_t ws_size,
                              hipStream_t stream)
{
    const float* x  = (const float*)d_in[0];
    const float* w1 = (const float*)d_in[1];
    const float* b1 = (const float*)d_in[2];
    const float* w2 = (const float*)d_in[3];
    const float* b2 = (const float*)d_in[4];

    const int MID = in_sizes[2];         // 2048
    const int H   = in_sizes[1] / MID;   // 4096
    const int M   = in_sizes[0] / H;     // 16384

    float* out = (float*)d_out;
    char* ws = (char*)d_ws;

    size_t logits_bytes = (size_t)M * NE * sizeof(float);
    float*  logits = (float*)ws;
    float*  acc    = (float*)(ws + logits_bytes);
    size_t  off_w1h = (logits_bytes + 64 + 255) & ~(size_t)255;
    size_t  w1t_bytes = (size_t)MID * H * sizeof(ushort);
    ushort* w1t_hi = (ushort*)(ws + off_w1h);
    ushort* w1t_lo = (ushort*)(ws + off_w1h + w1t_bytes);
    size_t  need_w1 = off_w1h + 2 * w1t_bytes;

    hipMemsetAsync(d_ws, 0, logits_bytes + 64, stream);

    const bool shape_ok = (M % BM == 0) && (MID % BN == 0) && (H % (2 * BK) == 0)
                          && (H % 32 == 0) && (MID % 32 == 0);

    if (ws_size >= need_w1 && shape_ok) {
        dim3 gridT(MID / 32, H / 32);
        decomp_w1<<<gridT, 256, 0, stream>>>(w1, w1t_hi, w1t_lo, H, MID);
        dim3 grid1(MID / BN, M / BM);   // N fastest -> x-strip L2 reuse
        gemm_fused<<<grid1, 256, 0, stream>>>(x, w1t_hi, w1t_lo, b1, w2,
                                              logits, M, H, MID);
    } else {
        dim3 grid1(MID / TN, M / TM);
        gemm1_fused<<<grid1, 256, 0, stream>>>(x, w1, b1, w2, logits, M, H, MID);
    }

    router_kernel<<<(M + 255) / 256, 256, 0, stream>>>(logits, b2, out, acc, M);
    aux_kernel<<<1, 64, 0, stream>>>(acc, out + (size_t)M * NE, 1.0f / (float)M);
}